// Round 12
// baseline (195.271 us; speedup 1.0000x reference)
//
#include <hip/hip_runtime.h>
#include <hip/hip_bf16.h>
#include <hip/hip_fp16.h>
#include <hip/hip_cooperative_groups.h>

namespace cg = cooperative_groups;

#define NN 2048
#define KK 8
#define DD 32
#define ZSZ (KK * NN * DD)  // 524288

// swizzled tile word address: row in [0,256), slot in [0,4) (16B units), conflict-free
#define TW(row, slot) (((row) << 4) + ((((slot) ^ (((row) >> 1) & 3))) << 2))

typedef __attribute__((ext_vector_type(8))) short short8;
typedef __attribute__((ext_vector_type(4))) short short4v;
typedef __attribute__((ext_vector_type(4))) float f32x4;
typedef __attribute__((ext_vector_type(4))) unsigned int u32x4;

union UU { u32x4 q; short8 v; unsigned int u[4]; };
union U2 { uint2 q; short4v v; unsigned int u[2]; };

__device__ __forceinline__ unsigned int bfr(float x) {
  unsigned int u = __float_as_uint(x);
  return (u + 0x7fffu + ((u >> 16) & 1u)) >> 16;
}
__device__ __forceinline__ float bf2f(unsigned int h) {  // bf16 bits -> f32
  return __uint_as_float(h << 16);
}
__device__ __forceinline__ unsigned int packp(float a, float b) {  // a->lo16, b->hi16
  union { __hip_bfloat162 h; unsigned int u; } cv;
  cv.h = __float22bfloat162_rn(make_float2(a, b));
  return cv.u;
}
__device__ __forceinline__ f32x4 MF(short8 a, short8 b, f32x4 c) {
  return __builtin_amdgcn_mfma_f32_16x16x32_bf16(a, b, c, 0, 0, 0);
}
__device__ __forceinline__ f32x4 MF16(short4v a, short4v b, f32x4 c) {
  return __builtin_amdgcn_mfma_f32_16x16x16bf16_1k(a, b, c, 0, 0, 0);
}
__device__ __forceinline__ short8 as_s8(u32x4 x) { UU u; u.q = x; return u.v; }

// Zthi global word order is PERMUTED within each 16-word (32-m) group:
// logical w = 8*sub + 2*g + e  ->  physical p = 4*g + 2*sub + e.
// Consequence: the LDS b128 at quad g of a row = {sub0 uint2, sub1 uint2} for
// m-slice g -> agg reads become one conflict-free ds_read_b128 (gram pattern)
// instead of two 4-way-conflicted b64s (r11 PMC: 2^22 conflicts == 4/b64-read).

// ===================== single cooperative kernel: all phases =====================
__global__ __launch_bounds__(256, 2) void mega_kernel(
    const float* feat, const float* W, const float* bias, const int* adj,
    unsigned short* Zghi, unsigned short* Zthi, unsigned int* mbits,
    __half* part, float* out) {
  __shared__ __align__(16) unsigned int lds[20480];  // 80 KB
  cg::grid_group grid = cg::this_grid();
  const int bx = blockIdx.x;
  const int t = threadIdx.x;
  const int w = t >> 6;
  const int lane = t & 63;
  const int l15 = lane & 15;
  const int g = lane >> 4;

  unsigned int* Zg = (unsigned int*)Zghi;
  unsigned int* Zt = (unsigned int*)Zthi;

  // ---------------- Phase P: projection (4 nodes) + adj bitmask ----------------
  {
    const int nb = bx * 4;
    const int k = t >> 5, c = t & 31;
    float* fsh = (float*)lds;
    if (t < 128) *(float4*)&fsh[4 * t] = *(const float4*)&feat[nb * 128 + 4 * t];
    float s[4];
#pragma unroll
    for (int j = 0; j < 4; ++j) s[j] = bias[k * DD + c];
    __syncthreads();
    const float* wp = W + (k * 128) * DD + c;
#pragma unroll 4
    for (int d = 0; d < 128; ++d) {
      float wv = wp[d * DD];
#pragma unroll
      for (int j = 0; j < 4; ++j) s[j] = fmaf(fsh[j * 128 + d], wv, s[j]);
    }
    unsigned int hi[4];
#pragma unroll
    for (int j = 0; j < 4; ++j) {
      float sq = s[j] * s[j];
#pragma unroll
      for (int off = 16; off > 0; off >>= 1) sq += __shfl_xor(sq, off, 32);
      float z = s[j] / fmaxf(sqrtf(sq), 1e-12f);
      hi[j] = bfr(z);
      Zghi[(k * NN + nb + j) * DD + c] = (unsigned short)hi[j];
    }
    // permuted Zthi write: logical words {2v, 2v+1}, v = bx&7 -> p0 = 4*(v&3)+2*(v>>2)
    {
      const size_t base = ((size_t)k * DD * NN + (size_t)c * NN) >> 1;
      const int v = bx & 7;
      const int p0 = 4 * (v & 3) + 2 * (v >> 2);
      *(uint2*)&Zt[base + (size_t)(bx >> 3) * 16 + p0] =
          make_uint2(hi[0] | (hi[1] << 16), hi[2] | (hi[3] << 16));
    }

    // adj bitmask: 8192 elements per block
    const int base = bx * 8192 + t;
#pragma unroll
    for (int q = 0; q < 4; ++q) {
      int v[8];
#pragma unroll
      for (int r = 0; r < 8; ++r) v[r] = adj[base + 256 * (8 * q + r)];
#pragma unroll
      for (int r = 0; r < 8; ++r) {
        int idx = base + 256 * (8 * q + r);
        unsigned long long b = __ballot(v[r] > 0);
        if (lane == 0) mbits[idx >> 5] = (unsigned int)b;
        if (lane == 32) mbits[idx >> 5] = (unsigned int)(b >> 32);
      }
    }
  }
  grid.sync();

  // XCD-pinned decomposition: all blocks of a chunk share bx%8 (one XCD)
  const int nblk = (bx >> 3) & 31;
  const int chunk = (bx & 7) * 2 + (bx >> 8);
  const int nw = nblk * 64 + w * 16;
  const int mchunk = chunk * 128;  // NS=4 steps x 32 m
  const int sqd = t & 3;
  const int sr0 = t >> 2;

#pragma unroll 1
  for (int it = 0; it < 4; ++it) {
    // ---------------- Phase I: gram + softmax(k) + aggregate ----------------
    {
      short8 A[KK];
#pragma unroll
      for (int k = 0; k < KK; ++k)
        A[k] = as_s8(*(const u32x4*)&Zg[(size_t)(k * NN + nw + l15) * 16 + 4 * g]);

      unsigned int mword[4];
      {
        uint4 m4 = *(const uint4*)&mbits[(size_t)(nw + l15) * 64 + (mchunk >> 5)];
        mword[0] = m4.x; mword[1] = m4.y; mword[2] = m4.z; mword[3] = m4.w;
      }

      f32x4 O[KK][2];
#pragma unroll
      for (int k = 0; k < KK; ++k)
#pragma unroll
        for (int ch = 0; ch < 2; ++ch) O[k][ch] = {0.0f, 0.0f, 0.0f, 0.0f};

      uint2 Bhi[KK][2];  // sub1 agg operands stashed by sub0's b128 read

      u32x4 Lgh[4], Lth[4];
      auto dl_g = [&](int mb) {
#pragma unroll
        for (int j = 0; j < 4; ++j) {
          int r = 64 * j + sr0;
          int k = r >> 5, rm = r & 31;
          Lgh[j] = *(const u32x4*)&Zg[(size_t)(k * NN + mb + rm) * 16 + 4 * sqd];
        }
      };
      auto wr_g = [&](int buf) {
#pragma unroll
        for (int j = 0; j < 4; ++j)
          *(u32x4*)&lds[buf * 4096 + TW(64 * j + sr0, sqd)] = Lgh[j];
      };
      auto dl_t = [&](int mb) {
#pragma unroll
        for (int j = 0; j < 4; ++j) {
          int r = 64 * j + sr0;
          int k = r >> 5, rm = r & 31;
          Lth[j] = *(const u32x4*)&Zt[(size_t)k * (NN * 16) + (size_t)rm * (NN / 2) + (mb >> 1) + 4 * sqd];
        }
      };
      auto wr_t = [&](int buf) {
#pragma unroll
        for (int j = 0; j < 4; ++j)
          *(u32x4*)&lds[12288 + buf * 4096 + TW(64 * j + sr0, sqd)] = Lth[j];
      };
      auto gram = [&](int gbuf, int sub, f32x4* S) {
#pragma unroll
        for (int k = 0; k < KK; ++k) {
          u32x4 bh = *(const u32x4*)&lds[gbuf * 4096 + TW(k * 32 + 16 * sub + l15, g)];
          f32x4 z = {0.0f, 0.0f, 0.0f, 0.0f};
          S[k] = MF(as_s8(bh), A[k], z);
        }
      };
      auto finish0 = [&](f32x4* S, int tbuf, unsigned int mw) {
#pragma unroll
        for (int r = 0; r < 4; ++r) {
          float e[KK];
          float sum = 0.0f;
#pragma unroll
          for (int k = 0; k < KK; ++k) { e[k] = __expf(S[k][r]); sum += e[k]; }
          float f = ((mw >> (4 * g + r)) & 1u) ? __builtin_amdgcn_rcpf(sum) : 0.0f;
#pragma unroll
          for (int k = 0; k < KK; ++k) S[k][r] = e[k] * f;
        }
#pragma unroll
        for (int k = 0; k < KK; ++k) {
          U2 pa;
          pa.u[0] = packp(S[k][0], S[k][1]);
          pa.u[1] = packp(S[k][2], S[k][3]);
#pragma unroll
          for (int ch = 0; ch < 2; ++ch) {
            int row = k * 32 + 16 * ch + l15;
            u32x4 q = *(const u32x4*)&lds[12288 + tbuf * 4096 + TW(row, g)];
            U2 bv; bv.u[0] = q.x; bv.u[1] = q.y;
            Bhi[k][ch] = make_uint2(q.z, q.w);
            O[k][ch] = MF16(pa.v, bv.v, O[k][ch]);
          }
        }
      };
      auto finish1 = [&](f32x4* S, unsigned int mw) {
#pragma unroll
        for (int r = 0; r < 4; ++r) {
          float e[KK];
          float sum = 0.0f;
#pragma unroll
          for (int k = 0; k < KK; ++k) { e[k] = __expf(S[k][r]); sum += e[k]; }
          float f = ((mw >> (16 + 4 * g + r)) & 1u) ? __builtin_amdgcn_rcpf(sum) : 0.0f;
#pragma unroll
          for (int k = 0; k < KK; ++k) S[k][r] = e[k] * f;
        }
#pragma unroll
        for (int k = 0; k < KK; ++k) {
          U2 pa;
          pa.u[0] = packp(S[k][0], S[k][1]);
          pa.u[1] = packp(S[k][2], S[k][3]);
#pragma unroll
          for (int ch = 0; ch < 2; ++ch) {
            U2 bv; bv.u[0] = Bhi[k][ch].x; bv.u[1] = Bhi[k][ch].y;
            O[k][ch] = MF16(pa.v, bv.v, O[k][ch]);
          }
        }
      };

      dl_g(mchunk); wr_g(0);
      dl_g(mchunk + 32); wr_g(1);
      dl_t(mchunk); wr_t(0);
      dl_g(mchunk + 64);
      dl_t(mchunk + 32);
      __syncthreads();

      f32x4 Scur[KK], Snxt[KK];
      gram(0, 0, Scur);

#pragma unroll
      for (int st = 0; st < 4; ++st) {
        if (st + 2 < 4) wr_g((st + 2) % 3);
        if (st + 1 < 4) wr_t((st + 1) & 1);
        if (st + 3 < 4) dl_g(mchunk + (st + 3) * 32);
        if (st + 2 < 4) dl_t(mchunk + (st + 2) * 32);
        const unsigned int mw = mword[st];

        gram(st % 3, 1, Snxt);
        finish0(Scur, st & 1, mw);
        if (st + 1 < 4) gram((st + 1) % 3, 0, Scur);
        finish1(Snxt, mw);
        __syncthreads();
      }

      __half* dst = part + (size_t)chunk * ZSZ;
#pragma unroll
      for (int k = 0; k < KK; ++k)
#pragma unroll
        for (int ch = 0; ch < 2; ++ch) {
          f32x4 o = O[k][ch];
#pragma unroll
          for (int r = 0; r < 4; ++r)
            dst[(size_t)(k * NN + nw + 4 * g + r) * DD + 16 * ch + l15] = __float2half_rn(o[r]);
        }
    }
    grid.sync();

    if (it < 3) {
      // ------- Phase R: reduce + l2norm + repack; u32 transpose buf, stride 37 -------
      {
        unsigned int* T32 = lds;  // [32][37] u32 overlay: <=2-way banks (free)
        const int k = bx >> 6, mt = bx & 63;
        const int m0 = mt * 32;
        const int mloc = t >> 3, c4 = t & 7;
        const size_t idx = (size_t)(k * NN + m0 + mloc) * DD + 4 * c4;
        uint2 zb = *(const uint2*)&Zghi[idx];
        float4 v;
        v.x = bf2f(zb.x & 0xffffu);
        v.y = __uint_as_float(zb.x & 0xffff0000u);
        v.z = bf2f(zb.y & 0xffffu);
        v.w = __uint_as_float(zb.y & 0xffff0000u);
#pragma unroll
        for (int j = 0; j < 16; ++j) {
          const __half2* ph = (const __half2*)&part[(size_t)j * ZSZ + idx];
          float2 a = __half22float2(ph[0]);
          float2 bb = __half22float2(ph[1]);
          v.x += a.x; v.y += a.y; v.z += bb.x; v.w += bb.y;
        }
        float sq = v.x * v.x + v.y * v.y + v.z * v.z + v.w * v.w;
        sq += __shfl_xor(sq, 1, 8);
        sq += __shfl_xor(sq, 2, 8);
        sq += __shfl_xor(sq, 4, 8);
        const float sc = 1.0f / fmaxf(sqrtf(sq), 1e-12f);
        float z[4] = {v.x * sc, v.y * sc, v.z * sc, v.w * sc};
        unsigned int hi[4];
#pragma unroll
        for (int e = 0; e < 4; ++e) {
          hi[e] = bfr(z[e]);
          T32[(4 * c4 + e) * 37 + mloc] = hi[e];
        }
        *(uint2*)&Zghi[idx] = make_uint2(hi[0] | (hi[1] << 16), hi[2] | (hi[3] << 16));
        __syncthreads();
        const int cloc = t >> 3, m4i = t & 7;
        unsigned int o0 = T32[cloc * 37 + 4 * m4i + 0] | (T32[cloc * 37 + 4 * m4i + 1] << 16);
        unsigned int o1 = T32[cloc * 37 + 4 * m4i + 2] | (T32[cloc * 37 + 4 * m4i + 3] << 16);
        // permuted Zthi write: logical pair w0=2*m4i -> p0 = 4*(m4i&3)+2*(m4i>>2)
        const size_t base = ((size_t)k * DD * NN + (size_t)cloc * NN) >> 1;
        const int p0 = 4 * (m4i & 3) + 2 * (m4i >> 2);
        *(uint2*)&Zt[base + (size_t)(m0 >> 1) + p0] = make_uint2(o0, o1);
        __syncthreads();
      }
      grid.sync();
    }
  }

  // ---------------- Phase O: residual + reduce + l2norm + output (4 nodes) ----------------
  {
    const int k = t >> 5, c = t & 31;
#pragma unroll
    for (int jj = 0; jj < 4; ++jj) {
      const int n = bx * 4 + jj;
      const size_t idx = (size_t)(k * NN + n) * DD + c;
      float v = bf2f((unsigned int)Zghi[idx]);
#pragma unroll
      for (int j = 0; j < 16; ++j) v += __half2float(part[(size_t)j * ZSZ + idx]);
      float sq = v * v;
#pragma unroll
      for (int off = 16; off > 0; off >>= 1) sq += __shfl_xor(sq, off, 32);
      out[n * (KK * DD) + t] = v / fmaxf(sqrtf(sq), 1e-12f);
    }
  }
}

// ========================= fallback multi-kernel path =========================
__global__ __launch_bounds__(256) void pm_kernel(const float* __restrict__ feat,
                                                 const float* __restrict__ W,
                                                 const float* __restrict__ bias,
                                                 unsigned short* __restrict__ Zghi,
                                                 unsigned short* __restrict__ Zthi,
                                                 const int* __restrict__ adj,
                                                 unsigned int* __restrict__ mbits) {
  __shared__ float fsh[1024];
  const int t = threadIdx.x;
  if (blockIdx.x < 256) {
    const int nb = blockIdx.x * 8;
    const int k = t >> 5, c = t & 31;
    *(float4*)&fsh[4 * t] = *(const float4*)&feat[nb * 128 + 4 * t];
    float s[8];
#pragma unroll
    for (int j = 0; j < 8; ++j) s[j] = bias[k * DD + c];
    const float* w = W + (k * 128) * DD + c;
    __syncthreads();
#pragma unroll 4
    for (int d = 0; d < 128; ++d) {
      float wv = w[d * DD];
#pragma unroll
      for (int j = 0; j < 8; ++j) s[j] = fmaf(fsh[j * 128 + d], wv, s[j]);
    }
    unsigned int hi[8];
#pragma unroll
    for (int j = 0; j < 8; ++j) {
      float sq = s[j] * s[j];
#pragma unroll
      for (int off = 16; off > 0; off >>= 1) sq += __shfl_xor(sq, off, 32);
      float z = s[j] / fmaxf(sqrtf(sq), 1e-12f);
      hi[j] = bfr(z);
      Zghi[(k * NN + nb + j) * DD + c] = (unsigned short)hi[j];
    }
    // permuted Zthi write: logical words {w0..w0+3}, w0=(nb>>1)&15 ->
    // physical {p0,p0+1,p0+4,p0+5}, p0 = 4*((w0>>1)&3)+2*(w0>>3)
    unsigned int* Zt = (unsigned int*)Zthi;
    const size_t base = ((size_t)k * DD * NN + (size_t)c * NN) >> 1;
    const int w0 = (nb >> 1) & 15;
    const int p0 = 4 * ((w0 >> 1) & 3) + 2 * (w0 >> 3);
    const size_t gb = base + (size_t)(nb >> 5) * 16;
    *(uint2*)&Zt[gb + p0] = make_uint2(hi[0] | (hi[1] << 16), hi[2] | (hi[3] << 16));
    *(uint2*)&Zt[gb + p0 + 4] = make_uint2(hi[4] | (hi[5] << 16), hi[6] | (hi[7] << 16));
  } else {
    const int base = (blockIdx.x - 256) * 1024 + t;
    const int lane = t & 63;
    int v[4];
#pragma unroll
    for (int rr = 0; rr < 4; ++rr) v[rr] = adj[base + 256 * rr];
#pragma unroll
    for (int rr = 0; rr < 4; ++rr) {
      int idx = base + 256 * rr;
      unsigned long long b = __ballot(v[rr] > 0);
      if (lane == 0) mbits[idx >> 5] = (unsigned int)b;
      if (lane == 32) mbits[idx >> 5] = (unsigned int)(b >> 32);
    }
  }
}

__global__ __launch_bounds__(256) void rp_kernel(const __half* __restrict__ part,
                                                 unsigned short* __restrict__ Zghi,
                                                 unsigned short* __restrict__ Zthi) {
  __shared__ unsigned int T32[32 * 37];
  const int t = threadIdx.x;
  const int k = blockIdx.x >> 6, mt = blockIdx.x & 63;
  const int m0 = mt * 32;
  const int mloc = t >> 3, c4 = t & 7;
  const size_t idx = (size_t)(k * NN + m0 + mloc) * DD + 4 * c4;
  uint2 zb = *(const uint2*)&Zghi[idx];
  float4 v;
  v.x = bf2f(zb.x & 0xffffu);
  v.y = __uint_as_float(zb.x & 0xffff0000u);
  v.z = bf2f(zb.y & 0xffffu);
  v.w = __uint_as_float(zb.y & 0xffff0000u);
#pragma unroll
  for (int j = 0; j < 16; ++j) {
    const __half2* ph = (const __half2*)&part[(size_t)j * ZSZ + idx];
    float2 a = __half22float2(ph[0]);
    float2 b = __half22float2(ph[1]);
    v.x += a.x; v.y += a.y; v.z += b.x; v.w += b.y;
  }
  float sq = v.x * v.x + v.y * v.y + v.z * v.z + v.w * v.w;
  sq += __shfl_xor(sq, 1, 8);
  sq += __shfl_xor(sq, 2, 8);
  sq += __shfl_xor(sq, 4, 8);
  const float sc = 1.0f / fmaxf(sqrtf(sq), 1e-12f);
  float z[4] = {v.x * sc, v.y * sc, v.z * sc, v.w * sc};
  unsigned int hi[4];
#pragma unroll
  for (int e = 0; e < 4; ++e) {
    hi[e] = bfr(z[e]);
    T32[(4 * c4 + e) * 37 + mloc] = hi[e];
  }
  *(uint2*)&Zghi[idx] = make_uint2(hi[0] | (hi[1] << 16), hi[2] | (hi[3] << 16));
  __syncthreads();
  const int cloc = t >> 3, m4 = t & 7;
  unsigned int o0 = T32[cloc * 37 + 4 * m4 + 0] | (T32[cloc * 37 + 4 * m4 + 1] << 16);
  unsigned int o1 = T32[cloc * 37 + 4 * m4 + 2] | (T32[cloc * 37 + 4 * m4 + 3] << 16);
  unsigned int* Zt = (unsigned int*)Zthi;
  const size_t base = ((size_t)k * DD * NN + (size_t)cloc * NN) >> 1;
  const int p0 = 4 * (m4 & 3) + 2 * (m4 >> 2);
  *(uint2*)&Zt[base + (size_t)(m0 >> 1) + p0] = make_uint2(o0, o1);
}

__global__ __launch_bounds__(256, 2) void iter_kernel(const unsigned short* __restrict__ Zghi,
                                                      const unsigned short* __restrict__ Zthi,
                                                      const unsigned int* __restrict__ mbits,
                                                      __half* __restrict__ part) {
  __shared__ __align__(16) unsigned int lds[20480];
  const int t = threadIdx.x;
  const int w = t >> 6;
  const int lane = t & 63;
  const int l15 = lane & 15;
  const int g = lane >> 4;
  const int bx = blockIdx.x;
  const int nblk = (bx >> 3) & 31;
  const int chunk = (bx & 7) * 2 + (bx >> 8);
  const int nw = nblk * 64 + w * 16;
  const int mchunk = chunk * 128;

  const unsigned int* Zg = (const unsigned int*)Zghi;
  const unsigned int* Zt = (const unsigned int*)Zthi;

  short8 A[KK];
#pragma unroll
  for (int k = 0; k < KK; ++k)
    A[k] = as_s8(*(const u32x4*)&Zg[(size_t)(k * NN + nw + l15) * 16 + 4 * g]);

  unsigned int mword[4];
  {
    uint4 m4 = *(const uint4*)&mbits[(size_t)(nw + l15) * 64 + (mchunk >> 5)];
    mword[0] = m4.x; mword[1] = m4.y; mword[2] = m4.z; mword[3] = m4.w;
  }

  f32x4 O[KK][2];
#pragma unroll
  for (int k = 0; k < KK; ++k)
#pragma unroll
    for (int ch = 0; ch < 2; ++ch) O[k][ch] = {0.0f, 0.0f, 0.0f, 0.0f};

  uint2 Bhi[KK][2];

  const int sqd = t & 3;
  const int sr0 = t >> 2;

  u32x4 Lgh[4], Lth[4];
  auto dl_g = [&](int mb) {
#pragma unroll
    for (int j = 0; j < 4; ++j) {
      int r = 64 * j + sr0;
      int k = r >> 5, rm = r & 31;
      Lgh[j] = *(const u32x4*)&Zg[(size_t)(k * NN + mb + rm) * 16 + 4 * sqd];
    }
  };
  auto wr_g = [&](int buf) {
#pragma unroll
    for (int j = 0; j < 4; ++j)
      *(u32x4*)&lds[buf * 4096 + TW(64 * j + sr0, sqd)] = Lgh[j];
  };
  auto dl_t = [&](int mb) {
#pragma unroll
    for (int j = 0; j < 4; ++j) {
      int r = 64 * j + sr0;
      int k = r >> 5, rm = r & 31;
      Lth[j] = *(const u32x4*)&Zt[(size_t)k * (NN * 16) + (size_t)rm * (NN / 2) + (mb >> 1) + 4 * sqd];
    }
  };
  auto wr_t = [&](int buf) {
#pragma unroll
    for (int j = 0; j < 4; ++j)
      *(u32x4*)&lds[12288 + buf * 4096 + TW(64 * j + sr0, sqd)] = Lth[j];
  };
  auto gram = [&](int gbuf, int sub, f32x4* S) {
#pragma unroll
    for (int k = 0; k < KK; ++k) {
      u32x4 bh = *(const u32x4*)&lds[gbuf * 4096 + TW(k * 32 + 16 * sub + l15, g)];
      f32x4 z = {0.0f, 0.0f, 0.0f, 0.0f};
      S[k] = MF(as_s8(bh), A[k], z);
    }
  };
  auto finish0 = [&](f32x4* S, int tbuf, unsigned int mw) {
#pragma unroll
    for (int r = 0; r < 4; ++r) {
      float e[KK];
      float sum = 0.0f;
#pragma unroll
      for (int k = 0; k < KK; ++k) { e[k] = __expf(S[k][r]); sum += e[k]; }
      float f = ((mw >> (4 * g + r)) & 1u) ? __builtin_amdgcn_rcpf(sum) : 0.0f;
#pragma unroll
      for (int k = 0; k < KK; ++k) S[k][r] = e[k] * f;
    }
#pragma unroll
    for (int k = 0; k < KK; ++k) {
      U2 pa;
      pa.u[0] = packp(S[k][0], S[k][1]);
      pa.u[1] = packp(S[k][2], S[k][3]);
#pragma unroll
      for (int ch = 0; ch < 2; ++ch) {
        int row = k * 32 + 16 * ch + l15;
        u32x4 q = *(const u32x4*)&lds[12288 + tbuf * 4096 + TW(row, g)];
        U2 bv; bv.u[0] = q.x; bv.u[1] = q.y;
        Bhi[k][ch] = make_uint2(q.z, q.w);
        O[k][ch] = MF16(pa.v, bv.v, O[k][ch]);
      }
    }
  };
  auto finish1 = [&](f32x4* S, unsigned int mw) {
#pragma unroll
    for (int r = 0; r < 4; ++r) {
      float e[KK];
      float sum = 0.0f;
#pragma unroll
      for (int k = 0; k < KK; ++k) { e[k] = __expf(S[k][r]); sum += e[k]; }
      float f = ((mw >> (16 + 4 * g + r)) & 1u) ? __builtin_amdgcn_rcpf(sum) : 0.0f;
#pragma unroll
      for (int k = 0; k < KK; ++k) S[k][r] = e[k] * f;
    }
#pragma unroll
    for (int k = 0; k < KK; ++k) {
      U2 pa;
      pa.u[0] = packp(S[k][0], S[k][1]);
      pa.u[1] = packp(S[k][2], S[k][3]);
#pragma unroll
      for (int ch = 0; ch < 2; ++ch) {
        U2 bv; bv.u[0] = Bhi[k][ch].x; bv.u[1] = Bhi[k][ch].y;
        O[k][ch] = MF16(pa.v, bv.v, O[k][ch]);
      }
    }
  };

  dl_g(mchunk); wr_g(0);
  dl_g(mchunk + 32); wr_g(1);
  dl_t(mchunk); wr_t(0);
  dl_g(mchunk + 64);
  dl_t(mchunk + 32);
  __syncthreads();

  f32x4 Scur[KK], Snxt[KK];
  gram(0, 0, Scur);

#pragma unroll
  for (int st = 0; st < 4; ++st) {
    if (st + 2 < 4) wr_g((st + 2) % 3);
    if (st + 1 < 4) wr_t((st + 1) & 1);
    if (st + 3 < 4) dl_g(mchunk + (st + 3) * 32);
    if (st + 2 < 4) dl_t(mchunk + (st + 2) * 32);
    const unsigned int mw = mword[st];

    gram(st % 3, 1, Snxt);
    finish0(Scur, st & 1, mw);
    if (st + 1 < 4) gram((st + 1) % 3, 0, Scur);
    finish1(Snxt, mw);
    __syncthreads();
  }

  __half* dst = part + (size_t)chunk * ZSZ;
#pragma unroll
  for (int k = 0; k < KK; ++k)
#pragma unroll
    for (int ch = 0; ch < 2; ++ch) {
      f32x4 o = O[k][ch];
#pragma unroll
      for (int r = 0; r < 4; ++r)
        dst[(size_t)(k * NN + nw + 4 * g + r) * DD + 16 * ch + l15] = __float2half_rn(o[r]);
    }
}

__global__ __launch_bounds__(256) void ro_kernel(const unsigned short* __restrict__ Zghi,
                                                 const __half* __restrict__ part,
                                                 float* __restrict__ out) {
  const int n = blockIdx.x, t = threadIdx.x;
  const int k = t >> 5, c = t & 31;
  const size_t idx = (size_t)(k * NN + n) * DD + c;
  float v = bf2f((unsigned int)Zghi[idx]);
#pragma unroll
  for (int j = 0; j < 16; ++j) v += __half2float(part[(size_t)j * ZSZ + idx]);
  float sq = v * v;
#pragma unroll
  for (int off = 16; off > 0; off >>= 1) sq += __shfl_xor(sq, off, 32);
  out[n * (KK * DD) + t] = v / fmaxf(sqrtf(sq), 1e-12f);
}

extern "C" void kernel_launch(void* const* d_in, const int* in_sizes, int n_in,
                              void* d_out, int out_size, void* d_ws, size_t ws_size,
                              hipStream_t stream) {
  const int* adj = (const int*)d_in[0];
  const float* feat = (const float*)d_in[1];
  const float* W = (const float*)d_in[2];
  const float* b = (const float*)d_in[3];
  float* out = (float*)d_out;

  unsigned short* Zghi = (unsigned short*)d_ws;
  unsigned short* Zthi = Zghi + ZSZ;
  unsigned int* mbits = (unsigned int*)(Zthi + ZSZ);
  __half* part = (__half*)(mbits + NN * 64);

  bool coop_ok = false;
  int maxb = 0;
  if (hipOccupancyMaxActiveBlocksPerMultiprocessor(&maxb, mega_kernel, 256, 0) == hipSuccess &&
      maxb >= 2) {
    void* kargs[] = {(void*)&feat, (void*)&W, (void*)&b, (void*)&adj,
                     (void*)&Zghi, (void*)&Zthi, (void*)&mbits, (void*)&part, (void*)&out};
    if (hipLaunchCooperativeKernel((const void*)mega_kernel, dim3(512), dim3(256), kargs, 0,
                                   stream) == hipSuccess)
      coop_ok = true;
  }
  if (coop_ok) return;

  pm_kernel<<<256 + 4096, 256, 0, stream>>>(feat, W, b, Zghi, Zthi, adj, mbits);
  for (int it = 0; it < 4; ++it) {
    iter_kernel<<<512, 256, 0, stream>>>(Zghi, Zthi, mbits, part);
    if (it < 3)
      rp_kernel<<<512, 256, 0, stream>>>(part, Zghi, Zthi);
    else
      ro_kernel<<<NN, 256, 0, stream>>>(Zghi, part, out);
  }
}

// Round 13
// 179.748 us; speedup vs baseline: 1.0864x; 1.0864x over previous
//
#include <hip/hip_runtime.h>
#include <hip/hip_bf16.h>
#include <hip/hip_fp16.h>
#include <hip/hip_cooperative_groups.h>

namespace cg = cooperative_groups;

#define NN 2048
#define KK 8
#define DD 32
#define ZSZ (KK * NN * DD)  // 524288

// swizzled tile word address: row in [0,256), slot in [0,4) (16B units), conflict-free
#define TW(row, slot) (((row) << 4) + ((((slot) ^ (((row) >> 1) & 3))) << 2))
// word-granular variant: wo in [0,16) words; same physical layout as TW staging
#define TW2(row, wo) (((row) << 4) + (((((wo) >> 2) ^ (((row) >> 1) & 3))) << 2) + ((wo) & 3))

typedef __attribute__((ext_vector_type(8))) short short8;
typedef __attribute__((ext_vector_type(4))) short short4v;
typedef __attribute__((ext_vector_type(4))) float f32x4;
typedef __attribute__((ext_vector_type(4))) unsigned int u32x4;

union UU { u32x4 q; short8 v; unsigned int u[4]; };
union U2 { uint2 q; short4v v; unsigned int u[2]; };

__device__ __forceinline__ unsigned int bfr(float x) {
  unsigned int u = __float_as_uint(x);
  return (u + 0x7fffu + ((u >> 16) & 1u)) >> 16;
}
__device__ __forceinline__ float bf2f(unsigned int h) {  // bf16 bits -> f32
  return __uint_as_float(h << 16);
}
__device__ __forceinline__ unsigned int packp(float a, float b) {  // a->lo16, b->hi16
  union { __hip_bfloat162 h; unsigned int u; } cv;
  cv.h = __float22bfloat162_rn(make_float2(a, b));
  return cv.u;
}
__device__ __forceinline__ f32x4 MF(short8 a, short8 b, f32x4 c) {
  return __builtin_amdgcn_mfma_f32_16x16x32_bf16(a, b, c, 0, 0, 0);
}
__device__ __forceinline__ f32x4 MF16(short4v a, short4v b, f32x4 c) {
  return __builtin_amdgcn_mfma_f32_16x16x16bf16_1k(a, b, c, 0, 0, 0);
}
__device__ __forceinline__ short8 as_s8(u32x4 x) { UU u; u.q = x; return u.v; }

// ===================== single cooperative kernel: all phases =====================
// 512 blocks x 256 thr, 2 blocks/CU (80 KB LDS). Phases separated by grid.sync():
// P(proj 4 nodes/blk + mask 8192/blk) | 4x[ I(iter) | R(rp) ] | O(ro 4 nodes/blk)
__global__ __launch_bounds__(256, 2) void mega_kernel(
    const float* feat, const float* W, const float* bias, const int* adj,
    unsigned short* Zghi, unsigned short* Zthi, unsigned int* mbits,
    __half* part, float* out) {
  __shared__ __align__(16) unsigned int lds[20480];  // 80 KB
  cg::grid_group grid = cg::this_grid();
  const int bx = blockIdx.x;
  const int t = threadIdx.x;
  const int w = t >> 6;
  const int lane = t & 63;
  const int l15 = lane & 15;
  const int g = lane >> 4;

  unsigned int* Zg = (unsigned int*)Zghi;
  unsigned int* Zt = (unsigned int*)Zthi;

  // ---------------- Phase P: projection (4 nodes) + adj bitmask ----------------
  {
    const int nb = bx * 4;
    const int k = t >> 5, c = t & 31;
    float* fsh = (float*)lds;
    if (t < 128) *(float4*)&fsh[4 * t] = *(const float4*)&feat[nb * 128 + 4 * t];
    float s[4];
#pragma unroll
    for (int j = 0; j < 4; ++j) s[j] = bias[k * DD + c];
    __syncthreads();
    const float* wp = W + (k * 128) * DD + c;
#pragma unroll 4
    for (int d = 0; d < 128; ++d) {
      float wv = wp[d * DD];
#pragma unroll
      for (int j = 0; j < 4; ++j) s[j] = fmaf(fsh[j * 128 + d], wv, s[j]);
    }
    unsigned int hi[4];
#pragma unroll
    for (int j = 0; j < 4; ++j) {
      float sq = s[j] * s[j];
#pragma unroll
      for (int off = 16; off > 0; off >>= 1) sq += __shfl_xor(sq, off, 32);
      float z = s[j] / fmaxf(sqrtf(sq), 1e-12f);
      hi[j] = bfr(z);
      Zghi[(k * NN + nb + j) * DD + c] = (unsigned short)hi[j];
    }
    *(uint2*)&Zthi[(size_t)k * DD * NN + (size_t)c * NN + nb] =
        make_uint2(hi[0] | (hi[1] << 16), hi[2] | (hi[3] << 16));

    // adj bitmask: 8192 elements per block
    const int base = bx * 8192 + t;
#pragma unroll
    for (int q = 0; q < 4; ++q) {
      int v[8];
#pragma unroll
      for (int r = 0; r < 8; ++r) v[r] = adj[base + 256 * (8 * q + r)];
#pragma unroll
      for (int r = 0; r < 8; ++r) {
        int idx = base + 256 * (8 * q + r);
        unsigned long long b = __ballot(v[r] > 0);
        if (lane == 0) mbits[idx >> 5] = (unsigned int)b;
        if (lane == 32) mbits[idx >> 5] = (unsigned int)(b >> 32);
      }
    }
  }
  grid.sync();

  const int nblk = bx & 31;
  const int chunk = bx >> 5;
  const int nw = nblk * 64 + w * 16;
  const int mchunk = chunk * 128;  // NS=4 steps x 32 m
  const int sqd = t & 3;
  const int sr0 = t >> 2;

#pragma unroll 1
  for (int it = 0; it < 4; ++it) {
    // ---------------- Phase I: gram + softmax(k) + aggregate (r9 body) ----------------
    {
      short8 A[KK];
#pragma unroll
      for (int k = 0; k < KK; ++k)
        A[k] = as_s8(*(const u32x4*)&Zg[(size_t)(k * NN + nw + l15) * 16 + 4 * g]);

      unsigned int mword[4];
      {
        uint4 m4 = *(const uint4*)&mbits[(size_t)(nw + l15) * 64 + (mchunk >> 5)];
        mword[0] = m4.x; mword[1] = m4.y; mword[2] = m4.z; mword[3] = m4.w;
      }

      f32x4 O[KK][2];
#pragma unroll
      for (int k = 0; k < KK; ++k)
#pragma unroll
        for (int ch = 0; ch < 2; ++ch) O[k][ch] = {0.0f, 0.0f, 0.0f, 0.0f};

      u32x4 Lgh[4], Lth[4];
      auto dl_g = [&](int mb) {
#pragma unroll
        for (int j = 0; j < 4; ++j) {
          int r = 64 * j + sr0;
          int k = r >> 5, rm = r & 31;
          Lgh[j] = *(const u32x4*)&Zg[(size_t)(k * NN + mb + rm) * 16 + 4 * sqd];
        }
      };
      auto wr_g = [&](int buf) {
#pragma unroll
        for (int j = 0; j < 4; ++j)
          *(u32x4*)&lds[buf * 4096 + TW(64 * j + sr0, sqd)] = Lgh[j];
      };
      auto dl_t = [&](int mb) {
#pragma unroll
        for (int j = 0; j < 4; ++j) {
          int r = 64 * j + sr0;
          int k = r >> 5, rm = r & 31;
          Lth[j] = *(const u32x4*)&Zt[(size_t)k * (NN * 16) + (size_t)rm * (NN / 2) + (mb >> 1) + 4 * sqd];
        }
      };
      auto wr_t = [&](int buf) {
#pragma unroll
        for (int j = 0; j < 4; ++j)
          *(u32x4*)&lds[12288 + buf * 4096 + TW(64 * j + sr0, sqd)] = Lth[j];
      };
      auto gram = [&](int gbuf, int sub, f32x4* S) {
#pragma unroll
        for (int k = 0; k < KK; ++k) {
          u32x4 bh = *(const u32x4*)&lds[gbuf * 4096 + TW(k * 32 + 16 * sub + l15, g)];
          f32x4 z = {0.0f, 0.0f, 0.0f, 0.0f};
          S[k] = MF(as_s8(bh), A[k], z);
        }
      };
      auto finish = [&](f32x4* S, int tbuf, int sub, unsigned int mw) {
#pragma unroll
        for (int r = 0; r < 4; ++r) {
          float e[KK];
          float sum = 0.0f;
#pragma unroll
          for (int k = 0; k < KK; ++k) { e[k] = __expf(S[k][r]); sum += e[k]; }
          float f = ((mw >> (16 * sub + 4 * g + r)) & 1u) ? __builtin_amdgcn_rcpf(sum) : 0.0f;
#pragma unroll
          for (int k = 0; k < KK; ++k) S[k][r] = e[k] * f;
        }
#pragma unroll
        for (int k = 0; k < KK; ++k) {
          U2 pa;
          pa.u[0] = packp(S[k][0], S[k][1]);
          pa.u[1] = packp(S[k][2], S[k][3]);
#pragma unroll
          for (int ch = 0; ch < 2; ++ch) {
            int row = k * 32 + 16 * ch + l15;
            U2 bv;
            bv.q = *(const uint2*)&lds[12288 + tbuf * 4096 + TW2(row, 8 * sub + 2 * g)];
            O[k][ch] = MF16(pa.v, bv.v, O[k][ch]);
          }
        }
      };

      // prologue: gram bufs 0,1 + tho buf 0 written; Lgh=gram(2), Lth=tho(1) held
      dl_g(mchunk); wr_g(0);
      dl_g(mchunk + 32); wr_g(1);
      dl_t(mchunk); wr_t(0);
      dl_g(mchunk + 64);
      dl_t(mchunk + 32);
      __syncthreads();

      f32x4 Scur[KK], Snxt[KK];
      gram(0, 0, Scur);

#pragma unroll
      for (int st = 0; st < 4; ++st) {
        if (st + 2 < 4) wr_g((st + 2) % 3);
        if (st + 1 < 4) wr_t((st + 1) & 1);
        if (st + 3 < 4) dl_g(mchunk + (st + 3) * 32);
        if (st + 2 < 4) dl_t(mchunk + (st + 2) * 32);
        const unsigned int mw = mword[st];

        gram(st % 3, 1, Snxt);
        finish(Scur, st & 1, 0, mw);
        if (st + 1 < 4) gram((st + 1) % 3, 0, Scur);
        finish(Snxt, st & 1, 1, mw);
        __syncthreads();
      }

      __half* dst = part + (size_t)chunk * ZSZ;
#pragma unroll
      for (int k = 0; k < KK; ++k)
#pragma unroll
        for (int ch = 0; ch < 2; ++ch) {
          f32x4 o = O[k][ch];
#pragma unroll
          for (int r = 0; r < 4; ++r)
            dst[(size_t)(k * NN + nw + 4 * g + r) * DD + 16 * ch + l15] = __float2half_rn(o[r]);
        }
    }
    grid.sync();

    if (it < 3) {
      // ---------------- Phase R: reduce + l2norm + repack (1:1 with rp) ----------------
      {
        unsigned short* T = (unsigned short*)lds;  // [32][33] overlay
        const int k = bx >> 6, mt = bx & 63;
        const int m0 = mt * 32;
        const int mloc = t >> 3, c4 = t & 7;
        const size_t idx = (size_t)(k * NN + m0 + mloc) * DD + 4 * c4;
        uint2 zb = *(const uint2*)&Zghi[idx];
        float4 v;
        v.x = bf2f(zb.x & 0xffffu);
        v.y = __uint_as_float(zb.x & 0xffff0000u);
        v.z = bf2f(zb.y & 0xffffu);
        v.w = __uint_as_float(zb.y & 0xffff0000u);
#pragma unroll
        for (int j = 0; j < 16; ++j) {
          const __half2* ph = (const __half2*)&part[(size_t)j * ZSZ + idx];
          float2 a = __half22float2(ph[0]);
          float2 bb = __half22float2(ph[1]);
          v.x += a.x; v.y += a.y; v.z += bb.x; v.w += bb.y;
        }
        float sq = v.x * v.x + v.y * v.y + v.z * v.z + v.w * v.w;
        sq += __shfl_xor(sq, 1, 8);
        sq += __shfl_xor(sq, 2, 8);
        sq += __shfl_xor(sq, 4, 8);
        const float sc = 1.0f / fmaxf(sqrtf(sq), 1e-12f);
        float z[4] = {v.x * sc, v.y * sc, v.z * sc, v.w * sc};
        unsigned int hi[4];
#pragma unroll
        for (int e = 0; e < 4; ++e) {
          hi[e] = bfr(z[e]);
          T[(4 * c4 + e) * 33 + mloc] = (unsigned short)hi[e];
        }
        *(uint2*)&Zghi[idx] = make_uint2(hi[0] | (hi[1] << 16), hi[2] | (hi[3] << 16));
        __syncthreads();
        const int cloc = t >> 3, m4i = t & 7;
        unsigned int o0 = (unsigned int)T[cloc * 33 + 4 * m4i + 0] |
                          ((unsigned int)T[cloc * 33 + 4 * m4i + 1] << 16);
        unsigned int o1 = (unsigned int)T[cloc * 33 + 4 * m4i + 2] |
                          ((unsigned int)T[cloc * 33 + 4 * m4i + 3] << 16);
        *(uint2*)&Zthi[(size_t)k * DD * NN + (size_t)cloc * NN + m0 + 4 * m4i] =
            make_uint2(o0, o1);
      }
      grid.sync();
    }
  }

  // ---------------- Phase O: residual + reduce + l2norm + output (4 nodes) ----------------
  {
    const int k = t >> 5, c = t & 31;
#pragma unroll
    for (int jj = 0; jj < 4; ++jj) {
      const int n = bx * 4 + jj;
      const size_t idx = (size_t)(k * NN + n) * DD + c;
      float v = bf2f((unsigned int)Zghi[idx]);
#pragma unroll
      for (int j = 0; j < 16; ++j) v += __half2float(part[(size_t)j * ZSZ + idx]);
      float sq = v * v;
#pragma unroll
      for (int off = 16; off > 0; off >>= 1) sq += __shfl_xor(sq, off, 32);
      out[n * (KK * DD) + t] = v / fmaxf(sqrtf(sq), 1e-12f);
    }
  }
}

// ========================= fallback multi-kernel path (r9) =========================
__global__ __launch_bounds__(256) void pm_kernel(const float* __restrict__ feat,
                                                 const float* __restrict__ W,
                                                 const float* __restrict__ bias,
                                                 unsigned short* __restrict__ Zghi,
                                                 unsigned short* __restrict__ Zthi,
                                                 const int* __restrict__ adj,
                                                 unsigned int* __restrict__ mbits) {
  __shared__ float fsh[1024];
  const int t = threadIdx.x;
  if (blockIdx.x < 256) {
    const int nb = blockIdx.x * 8;
    const int k = t >> 5, c = t & 31;
    *(float4*)&fsh[4 * t] = *(const float4*)&feat[nb * 128 + 4 * t];
    float s[8];
#pragma unroll
    for (int j = 0; j < 8; ++j) s[j] = bias[k * DD + c];
    const float* w = W + (k * 128) * DD + c;
    __syncthreads();
#pragma unroll 4
    for (int d = 0; d < 128; ++d) {
      float wv = w[d * DD];
#pragma unroll
      for (int j = 0; j < 8; ++j) s[j] = fmaf(fsh[j * 128 + d], wv, s[j]);
    }
    unsigned int hi[8];
#pragma unroll
    for (int j = 0; j < 8; ++j) {
      float sq = s[j] * s[j];
#pragma unroll
      for (int off = 16; off > 0; off >>= 1) sq += __shfl_xor(sq, off, 32);
      float z = s[j] / fmaxf(sqrtf(sq), 1e-12f);
      hi[j] = bfr(z);
      Zghi[(k * NN + nb + j) * DD + c] = (unsigned short)hi[j];
    }
    uint4 tp = make_uint4(hi[0] | (hi[1] << 16), hi[2] | (hi[3] << 16),
                          hi[4] | (hi[5] << 16), hi[6] | (hi[7] << 16));
    *(uint4*)&Zthi[(size_t)k * DD * NN + (size_t)c * NN + nb] = tp;
  } else {
    const int base = (blockIdx.x - 256) * 1024 + t;
    const int lane = t & 63;
    int v[4];
#pragma unroll
    for (int rr = 0; rr < 4; ++rr) v[rr] = adj[base + 256 * rr];
#pragma unroll
    for (int rr = 0; rr < 4; ++rr) {
      int idx = base + 256 * rr;
      unsigned long long b = __ballot(v[rr] > 0);
      if (lane == 0) mbits[idx >> 5] = (unsigned int)b;
      if (lane == 32) mbits[idx >> 5] = (unsigned int)(b >> 32);
    }
  }
}

__global__ __launch_bounds__(256) void rp_kernel(const __half* __restrict__ part,
                                                 unsigned short* __restrict__ Zghi,
                                                 unsigned short* __restrict__ Zthi) {
  __shared__ unsigned short T[DD][33];
  const int t = threadIdx.x;
  const int k = blockIdx.x >> 6, mt = blockIdx.x & 63;
  const int m0 = mt * 32;
  const int mloc = t >> 3, c4 = t & 7;
  const size_t idx = (size_t)(k * NN + m0 + mloc) * DD + 4 * c4;
  uint2 zb = *(const uint2*)&Zghi[idx];
  float4 v;
  v.x = bf2f(zb.x & 0xffffu);
  v.y = __uint_as_float(zb.x & 0xffff0000u);
  v.z = bf2f(zb.y & 0xffffu);
  v.w = __uint_as_float(zb.y & 0xffff0000u);
#pragma unroll
  for (int j = 0; j < 16; ++j) {
    const __half2* ph = (const __half2*)&part[(size_t)j * ZSZ + idx];
    float2 a = __half22float2(ph[0]);
    float2 b = __half22float2(ph[1]);
    v.x += a.x; v.y += a.y; v.z += b.x; v.w += b.y;
  }
  float sq = v.x * v.x + v.y * v.y + v.z * v.z + v.w * v.w;
  sq += __shfl_xor(sq, 1, 8);
  sq += __shfl_xor(sq, 2, 8);
  sq += __shfl_xor(sq, 4, 8);
  const float sc = 1.0f / fmaxf(sqrtf(sq), 1e-12f);
  float z[4] = {v.x * sc, v.y * sc, v.z * sc, v.w * sc};
  unsigned int hi[4];
#pragma unroll
  for (int e = 0; e < 4; ++e) {
    hi[e] = bfr(z[e]);
    T[4 * c4 + e][mloc] = (unsigned short)hi[e];
  }
  *(uint2*)&Zghi[idx] = make_uint2(hi[0] | (hi[1] << 16), hi[2] | (hi[3] << 16));
  __syncthreads();
  const int cloc = t >> 3, m4 = t & 7;
  unsigned int o0 = (unsigned int)T[cloc][4 * m4 + 0] | ((unsigned int)T[cloc][4 * m4 + 1] << 16);
  unsigned int o1 = (unsigned int)T[cloc][4 * m4 + 2] | ((unsigned int)T[cloc][4 * m4 + 3] << 16);
  *(uint2*)&Zthi[(size_t)k * DD * NN + (size_t)cloc * NN + m0 + 4 * m4] = make_uint2(o0, o1);
}

__global__ __launch_bounds__(256, 2) void iter_kernel(const unsigned short* __restrict__ Zghi,
                                                      const unsigned short* __restrict__ Zthi,
                                                      const unsigned int* __restrict__ mbits,
                                                      __half* __restrict__ part) {
  __shared__ __align__(16) unsigned int lds[20480];
  const int t = threadIdx.x;
  const int w = t >> 6;
  const int lane = t & 63;
  const int l15 = lane & 15;
  const int g = lane >> 4;
  const int nw = blockIdx.x * 64 + w * 16;
  const int mchunk = blockIdx.y * 128;

  const unsigned int* Zg = (const unsigned int*)Zghi;
  const unsigned int* Zt = (const unsigned int*)Zthi;

  short8 A[KK];
#pragma unroll
  for (int k = 0; k < KK; ++k)
    A[k] = as_s8(*(const u32x4*)&Zg[(size_t)(k * NN + nw + l15) * 16 + 4 * g]);

  unsigned int mword[4];
  {
    uint4 m4 = *(const uint4*)&mbits[(size_t)(nw + l15) * 64 + (mchunk >> 5)];
    mword[0] = m4.x; mword[1] = m4.y; mword[2] = m4.z; mword[3] = m4.w;
  }

  f32x4 O[KK][2];
#pragma unroll
  for (int k = 0; k < KK; ++k)
#pragma unroll
    for (int ch = 0; ch < 2; ++ch) O[k][ch] = {0.0f, 0.0f, 0.0f, 0.0f};

  const int sqd = t & 3;
  const int sr0 = t >> 2;

  u32x4 Lgh[4], Lth[4];
  auto dl_g = [&](int mb) {
#pragma unroll
    for (int j = 0; j < 4; ++j) {
      int r = 64 * j + sr0;
      int k = r >> 5, rm = r & 31;
      Lgh[j] = *(const u32x4*)&Zg[(size_t)(k * NN + mb + rm) * 16 + 4 * sqd];
    }
  };
  auto wr_g = [&](int buf) {
#pragma unroll
    for (int j = 0; j < 4; ++j)
      *(u32x4*)&lds[buf * 4096 + TW(64 * j + sr0, sqd)] = Lgh[j];
  };
  auto dl_t = [&](int mb) {
#pragma unroll
    for (int j = 0; j < 4; ++j) {
      int r = 64 * j + sr0;
      int k = r >> 5, rm = r & 31;
      Lth[j] = *(const u32x4*)&Zt[(size_t)k * (NN * 16) + (size_t)rm * (NN / 2) + (mb >> 1) + 4 * sqd];
    }
  };
  auto wr_t = [&](int buf) {
#pragma unroll
    for (int j = 0; j < 4; ++j)
      *(u32x4*)&lds[12288 + buf * 4096 + TW(64 * j + sr0, sqd)] = Lth[j];
  };
  auto gram = [&](int gbuf, int sub, f32x4* S) {
#pragma unroll
    for (int k = 0; k < KK; ++k) {
      u32x4 bh = *(const u32x4*)&lds[gbuf * 4096 + TW(k * 32 + 16 * sub + l15, g)];
      f32x4 z = {0.0f, 0.0f, 0.0f, 0.0f};
      S[k] = MF(as_s8(bh), A[k], z);
    }
  };
  auto finish = [&](f32x4* S, int tbuf, int sub, unsigned int mw) {
#pragma unroll
    for (int r = 0; r < 4; ++r) {
      float e[KK];
      float sum = 0.0f;
#pragma unroll
      for (int k = 0; k < KK; ++k) { e[k] = __expf(S[k][r]); sum += e[k]; }
      float f = ((mw >> (16 * sub + 4 * g + r)) & 1u) ? __builtin_amdgcn_rcpf(sum) : 0.0f;
#pragma unroll
      for (int k = 0; k < KK; ++k) S[k][r] = e[k] * f;
    }
#pragma unroll
    for (int k = 0; k < KK; ++k) {
      U2 pa;
      pa.u[0] = packp(S[k][0], S[k][1]);
      pa.u[1] = packp(S[k][2], S[k][3]);
#pragma unroll
      for (int ch = 0; ch < 2; ++ch) {
        int row = k * 32 + 16 * ch + l15;
        U2 bv;
        bv.q = *(const uint2*)&lds[12288 + tbuf * 4096 + TW2(row, 8 * sub + 2 * g)];
        O[k][ch] = MF16(pa.v, bv.v, O[k][ch]);
      }
    }
  };

  dl_g(mchunk); wr_g(0);
  dl_g(mchunk + 32); wr_g(1);
  dl_t(mchunk); wr_t(0);
  dl_g(mchunk + 64);
  dl_t(mchunk + 32);
  __syncthreads();

  f32x4 Scur[KK], Snxt[KK];
  gram(0, 0, Scur);

#pragma unroll
  for (int st = 0; st < 4; ++st) {
    if (st + 2 < 4) wr_g((st + 2) % 3);
    if (st + 1 < 4) wr_t((st + 1) & 1);
    if (st + 3 < 4) dl_g(mchunk + (st + 3) * 32);
    if (st + 2 < 4) dl_t(mchunk + (st + 2) * 32);
    const unsigned int mw = mword[st];

    gram(st % 3, 1, Snxt);
    finish(Scur, st & 1, 0, mw);
    if (st + 1 < 4) gram((st + 1) % 3, 0, Scur);
    finish(Snxt, st & 1, 1, mw);
    __syncthreads();
  }

  __half* dst = part + (size_t)blockIdx.y * ZSZ;
#pragma unroll
  for (int k = 0; k < KK; ++k)
#pragma unroll
    for (int ch = 0; ch < 2; ++ch) {
      f32x4 o = O[k][ch];
#pragma unroll
      for (int r = 0; r < 4; ++r)
        dst[(size_t)(k * NN + nw + 4 * g + r) * DD + 16 * ch + l15] = __float2half_rn(o[r]);
    }
}

__global__ __launch_bounds__(256) void ro_kernel(const unsigned short* __restrict__ Zghi,
                                                 const __half* __restrict__ part,
                                                 float* __restrict__ out) {
  const int n = blockIdx.x, t = threadIdx.x;
  const int k = t >> 5, c = t & 31;
  const size_t idx = (size_t)(k * NN + n) * DD + c;
  float v = bf2f((unsigned int)Zghi[idx]);
#pragma unroll
  for (int j = 0; j < 16; ++j) v += __half2float(part[(size_t)j * ZSZ + idx]);
  float sq = v * v;
#pragma unroll
  for (int off = 16; off > 0; off >>= 1) sq += __shfl_xor(sq, off, 32);
  out[n * (KK * DD) + t] = v / fmaxf(sqrtf(sq), 1e-12f);
}

extern "C" void kernel_launch(void* const* d_in, const int* in_sizes, int n_in,
                              void* d_out, int out_size, void* d_ws, size_t ws_size,
                              hipStream_t stream) {
  const int* adj = (const int*)d_in[0];
  const float* feat = (const float*)d_in[1];
  const float* W = (const float*)d_in[2];
  const float* b = (const float*)d_in[3];
  float* out = (float*)d_out;

  unsigned short* Zghi = (unsigned short*)d_ws;
  unsigned short* Zthi = Zghi + ZSZ;
  unsigned int* mbits = (unsigned int*)(Zthi + ZSZ);
  __half* part = (__half*)(mbits + NN * 64);

  // cooperative mega-kernel path: 512 blocks (2/CU exact), 8 grid syncs, 1 launch
  bool coop_ok = false;
  int maxb = 0;
  if (hipOccupancyMaxActiveBlocksPerMultiprocessor(&maxb, mega_kernel, 256, 0) == hipSuccess &&
      maxb >= 2) {
    void* kargs[] = {(void*)&feat, (void*)&W, (void*)&b, (void*)&adj,
                     (void*)&Zghi, (void*)&Zthi, (void*)&mbits, (void*)&part, (void*)&out};
    if (hipLaunchCooperativeKernel((const void*)mega_kernel, dim3(512), dim3(256), kargs, 0,
                                   stream) == hipSuccess)
      coop_ok = true;
  }
  if (coop_ok) return;

  // fallback: r9 multi-kernel path
  pm_kernel<<<256 + 4096, 256, 0, stream>>>(feat, W, b, Zghi, Zthi, adj, mbits);
  for (int it = 0; it < 4; ++it) {
    iter_kernel<<<dim3(32, 16), 256, 0, stream>>>(Zghi, Zthi, mbits, part);
    if (it < 3)
      rp_kernel<<<512, 256, 0, stream>>>(part, Zghi, Zthi);
    else
      ro_kernel<<<NN, 256, 0, stream>>>(Zghi, part, out);
  }
}